// Round 8
// baseline (295.796 us; speedup 1.0000x reference)
//
#include <hip/hip_runtime.h>

// ---------------------------------------------------------------------------
// QuantumLayer: B=16384 states of 10 qubits (DIM=1024 complex amps).
// One wave (64 lanes) per state; each lane holds 16 complex amps in VGPRs.
// Amp index k (10 bits): lane = k>>4 (storage bits 9..4), reg = k&15 (bits 3..0).
// CNOTs are compile-time GF(2) index relabeling (matrix S); each Rot gate acts
// along direction v = S e_b with side bit parity(R & k), R = row of S^{-1}.
// R8: == R7 (DS-bound -> move cross-lane transport to the idle VALU pipe via
// DPP / permlane32_swap) with the permlane partner-select FIXED: R7 assumed
// an orientation for permlane32_swap's (r.x, r.y); actual HW delivered own
// value. Fix: partner = r.x ^ r.y ^ own  (exact, orientation-independent,
// since {r.x, r.y} == {own, partner} per lane under either orientation).
// Scalar ar/ai state (R6's f2 packing regressed; reverted).
// ---------------------------------------------------------------------------

namespace {

constexpr int NQ = 10;
constexpr int NGATES = 50;   // Rot gates of layers 1..5 (layer 0 fused into init)

struct Sched {
  unsigned v[NGATES];
  unsigned R[NGATES];
  unsigned Rfin[NQ];
  bool ok;
};

constexpr int par(unsigned x) { int p = 0; while (x) { p ^= 1; x &= x - 1; } return p; }

constexpr Sched make_sched() {
  Sched s{};
  unsigned cols[NQ] = {};
  unsigned rows[NQ] = {};
  for (int b = 0; b < NQ; ++b) { cols[b] = 1u << b; rows[b] = 1u << b; }
  int g = 0;
  for (int l = 0; l < 6; ++l) {
    if (l > 0) {
      for (int w = 0; w < NQ; ++w) {
        int b = 9 - w;
        s.v[g] = cols[b];
        s.R[g] = rows[b];
        ++g;
      }
    }
    int r = l % 9 + 1;
    for (int w = 0; w < NQ; ++w) {
      int c = w, t = (w + r) % NQ;
      int cb = 9 - c, tb = 9 - t;
      cols[cb] ^= cols[tb];
      rows[tb] ^= rows[cb];
    }
  }
  for (int b = 0; b < NQ; ++b) s.Rfin[b] = rows[b];
  bool ok = true;
  for (int a = 0; a < NQ; ++a)
    for (int b = 0; b < NQ; ++b)
      if (par(rows[a] & cols[b]) != (a == b ? 1 : 0)) ok = false;
  s.ok = ok;
  return s;
}

constexpr Sched SCH = make_sched();
static_assert(SCH.ok, "GF(2) schedule inconsistent");

// DPP mov count to realize xor-mask m (1..15) within a 16-lane row
constexpr int dppc(int m) {
  if (m == 0) return 0;
  if (m == 1 || m == 2 || m == 3 || m == 7 || m == 15) return 1;
  if (m == 9 || m == 10 || m == 11) return 3;
  return 2;
}

} // namespace

__device__ float g_rots[60 * 8];

__global__ void setup_rots_kernel(const float* __restrict__ wts) {
  int idx = threadIdx.x;
  if (idx < 60) {
    float phi = wts[idx * 3 + 0], th = wts[idx * 3 + 1], om = wts[idx * 3 + 2];
    float c, sn;
    sincosf(0.5f * th, &sn, &c);
    float ca, sa, cb, sb;
    sincosf(0.5f * (phi + om), &sa, &ca);
    sincosf(0.5f * (phi - om), &sb, &cb);
    float* o = g_rots + idx * 8;
    o[0] =  ca * c;   o[1] = -sa * c;
    o[2] = -cb * sn;  o[3] = -sb * sn;
    o[4] =  cb * sn;  o[5] = -sb * sn;
    o[6] =  ca * c;   o[7] =  sa * c;
  }
}

// ---- cross-lane primitives -------------------------------------------------
typedef unsigned uint2v __attribute__((ext_vector_type(2)));

template<int CTRL>
__device__ __forceinline__ float dpp_mov(float v) {
  return __int_as_float(__builtin_amdgcn_update_dpp(
      0, __float_as_int(v), CTRL, 0xF, 0xF, true));
}

// xor-M within each 16-lane row, VALU-only (1-3 dpp movs)
template<int M>
__device__ __forceinline__ float dxor(float v) {
  static_assert(M >= 1 && M <= 15, "dxor mask");
  if constexpr (M == 1)       return dpp_mov<0xB1>(v);    // quad_perm [1,0,3,2]
  else if constexpr (M == 2)  return dpp_mov<0x4E>(v);    // quad_perm [2,3,0,1]
  else if constexpr (M == 3)  return dpp_mov<0x1B>(v);    // quad_perm [3,2,1,0]
  else if constexpr (M == 7)  return dpp_mov<0x141>(v);   // row_half_mirror
  else if constexpr (M == 15) return dpp_mov<0x140>(v);   // row_mirror
  else if constexpr (M == 8)  return dxor<7>(dxor<15>(v));
  else if constexpr ((M & ~3) == 4)  return dxor<M ^ 7>(dxor<7>(v));    // 4,5,6
  else if constexpr ((M & ~3) == 12) return dxor<M ^ 15>(dxor<15>(v));  // 12,13,14
  else return dxor<M ^ 8>(dxor<8>(v));                                  // 9,10,11
}

__device__ __forceinline__ float bperm1(int baddr, float v) {
  return __int_as_float(__builtin_amdgcn_ds_bpermute(baddr, __float_as_int(v)));
}

template<int M>
__device__ __forceinline__ float swz1(float v) {
  // BitMode xor swizzle within 32-lane groups: offset = (xor<<10) | and_mask 0x1F
  return __int_as_float(__builtin_amdgcn_ds_swizzle(__float_as_int(v), (M << 10) | 0x1F));
}

// partner fetch along lane-xor VH, routed to the cheapest pipe
template<int VH>
__device__ __forceinline__ float xfetch(float v, int baddr) {
  constexpr int lo = VH & 15;
  if constexpr (VH == 0) {
    return v;
  } else if constexpr (VH < 16) {
    if constexpr (dppc(lo) <= 2) return dxor<lo>(v);     // VALU
    else                         return swz1<VH>(v);     // DS (3-dpp masks)
  } else if constexpr (VH < 32) {
    return swz1<VH>(v);                                  // DS (bit4 masks)
  } else if constexpr ((VH & 16) == 0 && dppc(lo) <= 2) {
    // 32|lo with cheap lo: (optional dpp) + permlane32_swap + xor-combine.
    // {r.x, r.y} == {own, partner} per lane under either HW orientation, so
    // partner = r.x ^ r.y ^ own  -- exact, orientation-independent. VALU-only.
    float t = v;
    if constexpr (lo != 0) t = dxor<lo>(t);
    const unsigned tb = __float_as_uint(t);
    uint2v r = __builtin_amdgcn_permlane32_swap(tb, tb, false, false);
    return __uint_as_float(r.x ^ r.y ^ tb);
  } else {
    return bperm1(baddr, v);                             // DS fallback
  }
}

template<int VH>
constexpr bool needs_bperm() {
  return (VH >= 32) && (((VH & 16) != 0) || dppc(VH & 15) > 2);
}

// 6-step DPP wave reduction; total lands in lane 63
__device__ __forceinline__ float red64_l63(float t) {
  t += dpp_mov<0x111>(t);   // row_shr:1
  t += dpp_mov<0x112>(t);   // row_shr:2
  t += dpp_mov<0x114>(t);   // row_shr:4
  t += dpp_mov<0x118>(t);   // row_shr:8
  t += dpp_mov<0x142>(t);   // row_bcast:15
  t += dpp_mov<0x143>(t);   // row_bcast:31
  return t;
}

// reduction broadcast to all lanes (via lane-63 readlane)
__device__ __forceinline__ float red64_all(float t) {
  return __int_as_float(__builtin_amdgcn_readlane(
      __float_as_int(red64_l63(t)), 63));
}

// ---- one Rot gate along compile-time direction v, side-row R ---------------
template<int G>
__device__ __forceinline__ void apply_gate(const float4 uA, const float4 uB,
                                           float (&ar)[16], float (&ai)[16],
                                           const int lane) {
  constexpr int v  = (int)SCH.v[G];
  constexpr int R  = (int)SCH.R[G];
  constexpr int vl = v & 15, vh = v >> 4;
  constexpr int Rl = R & 15, Rh = R >> 4;

  bool ph = false;
  if constexpr (Rh != 0) ph = (__popc(lane & Rh) & 1) != 0;
  // class A: parity(i&Rl)==0 -> side==ph ; class B: side==!ph
  const float dAr = ph ? uB.z : uA.x, dAi = ph ? uB.w : uA.y;
  const float oAr = ph ? uB.x : uA.z, oAi = ph ? uB.y : uA.w;
  const float dBr = ph ? uA.x : uB.z, dBi = ph ? uA.y : uB.w;
  const float oBr = ph ? uA.z : uB.x, oBi = ph ? uA.w : uB.y;

  if constexpr (vh == 0) {
    // in-register pairs (i, i^vl)
#pragma unroll
    for (int i = 0; i < 16; ++i) {
      const int j = i ^ vl;
      if (j > i) {
        const bool ci = (__popc(i & Rl) & 1) != 0;   // compile-time after unroll
        const bool cj = (__popc(j & Rl) & 1) != 0;
        const float d0r = ci ? dBr : dAr, d0i = ci ? dBi : dAi;
        const float o0r = ci ? oBr : oAr, o0i = ci ? oBi : oAi;
        const float d1r = cj ? dBr : dAr, d1i = cj ? dBi : dAi;
        const float o1r = cj ? oBr : oAr, o1i = cj ? oBi : oAi;
        const float xr = ar[i], xi = ai[i], yr = ar[j], yi = ai[j];
        ar[i] = d0r * xr - d0i * xi + o0r * yr - o0i * yi;
        ai[i] = d0r * xi + d0i * xr + o0r * yi + o0i * yr;
        ar[j] = d1r * yr - d1i * yi + o1r * xr - o1i * xi;
        ai[j] = d1r * yi + d1i * yr + o1r * xi + o1i * xr;
      }
    }
  } else {
    int baddr = 0;
    if constexpr (needs_bperm<vh>()) baddr = (lane ^ vh) << 2;

    if constexpr (vl == 0) {
      // pure cross-lane: partner (lane^vh, i)
#pragma unroll
      for (int i = 0; i < 16; ++i) {
        const float pr = xfetch<vh>(ar[i], baddr);
        const float pi = xfetch<vh>(ai[i], baddr);
        const bool ci = (__popc(i & Rl) & 1) != 0;
        const float ddr = ci ? dBr : dAr, ddi = ci ? dBi : dAi;
        const float oor = ci ? oBr : oAr, ooi = ci ? oBi : oAi;
        const float xr = ar[i], xi = ai[i];
        ar[i] = ddr * xr - ddi * xi + oor * pr - ooi * pi;
        ai[i] = ddr * xi + ddi * xr + oor * pi + ooi * pr;
      }
    } else {
      // mixed: (lane,i) pairs with (lane^vh, i^vl); fetch before write per pair
#pragma unroll
      for (int i = 0; i < 16; ++i) {
        const int j = i ^ vl;
        if (j > i) {
          const float qjr = xfetch<vh>(ar[j], baddr);
          const float qji = xfetch<vh>(ai[j], baddr);
          const float qir = xfetch<vh>(ar[i], baddr);
          const float qii = xfetch<vh>(ai[i], baddr);
          const bool ci = (__popc(i & Rl) & 1) != 0;
          const bool cj = (__popc(j & Rl) & 1) != 0;
          const float d0r = ci ? dBr : dAr, d0i = ci ? dBi : dAi;
          const float o0r = ci ? oBr : oAr, o0i = ci ? oBi : oAi;
          const float d1r = cj ? dBr : dAr, d1i = cj ? dBi : dAi;
          const float o1r = cj ? oBr : oAr, o1i = cj ? oBi : oAi;
          const float xr = ar[i], xi = ai[i], yr = ar[j], yi = ai[j];
          ar[i] = d0r * xr - d0i * xi + o0r * qjr - o0i * qji;
          ai[i] = d0r * xi + d0i * xr + o0r * qji + o0i * qjr;
          ar[j] = d1r * yr - d1i * yi + o1r * qir - o1i * qii;
          ai[j] = d1r * yi + d1i * yr + o1r * qii + o1i * qir;
        }
      }
    }
  }
}

// Distance-1 pipeline for coefficient loads.
template<int G>
__device__ __forceinline__ void run_gates(const float4 uA, const float4 uB,
                                          float (&ar)[16], float (&ai)[16],
                                          const int lane) {
  float4 nA, nB;
  if constexpr (G + 1 < NGATES) {
    nA = *(const float4*)(g_rots + (NQ + G + 1) * 8);
    nB = *(const float4*)(g_rots + (NQ + G + 1) * 8 + 4);
  }
  apply_gate<G>(uA, uB, ar, ai, lane);
  if constexpr (G + 1 < NGATES) run_gates<G + 1>(nA, nB, ar, ai, lane);
}

__launch_bounds__(256)
__global__ void qlayer_kernel(const float* __restrict__ x,
                              const float* __restrict__ W,
                              const float* __restrict__ bias,
                              float* __restrict__ out) {
  const int lane = threadIdx.x & 63;
  const int s = blockIdx.x * 4 + (threadIdx.x >> 6);

  // ---- angles = x @ W^T + b ; RX cos/sin ----------------------------------
  const float xl = x[s * 64 + lane];
  float wl[NQ];
#pragma unroll
  for (int w = 0; w < NQ; ++w) wl[w] = W[w * 64 + lane];

  float cw[NQ], sw[NQ];
#pragma unroll
  for (int w = 0; w < NQ; ++w) {
    const float p = red64_all(xl * wl[w]);
    const float half = 0.5f * (p + bias[w]);
    float ss, cc;
    __sincosf(half, &ss, &cc);
    sw[w] = ss; cw[w] = cc;
  }

  // ---- fused per-qubit vector g_w = Rot0_w * RX_w * |0> -------------------
  float g0r[NQ], g0i[NQ], g1r[NQ], g1i[NQ];
#pragma unroll
  for (int w = 0; w < NQ; ++w) {
    const float4 uA = *(const float4*)(g_rots + w * 8);
    const float4 uB = *(const float4*)(g_rots + w * 8 + 4);
    const float c = cw[w], sn = sw[w];
    g0r[w] = uA.x * c + uA.w * sn;
    g0i[w] = uA.y * c - uA.z * sn;
    g1r[w] = uB.x * c + uB.w * sn;
    g1i[w] = uB.y * c - uB.z * sn;
  }

  // ---- product state ------------------------------------------------------
  float Fr, Fi;
  {
    const int b0 = (lane >> 5) & 1;
    Fr = b0 ? g1r[0] : g0r[0];
    Fi = b0 ? g1i[0] : g0i[0];
#pragma unroll
    for (int w = 1; w < 6; ++w) {
      const int bt = (lane >> (5 - w)) & 1;
      const float gr = bt ? g1r[w] : g0r[w];
      const float gi = bt ? g1i[w] : g0i[w];
      const float nr = Fr * gr - Fi * gi;
      const float ni = Fr * gi + Fi * gr;
      Fr = nr; Fi = ni;
    }
  }

  float ar[16], ai[16];
  {
    float thr[4], thi[4], tlr[4], tli[4];
#pragma unroll
    for (int a2 = 0; a2 < 4; ++a2) {
      const int bh = (a2 >> 1) & 1, bl = a2 & 1;
      {
        const float xr = bh ? g1r[6] : g0r[6], xi = bh ? g1i[6] : g0i[6];
        const float yr = bl ? g1r[7] : g0r[7], yi = bl ? g1i[7] : g0i[7];
        thr[a2] = xr * yr - xi * yi; thi[a2] = xr * yi + xi * yr;
      }
      {
        const float xr = bh ? g1r[8] : g0r[8], xi = bh ? g1i[8] : g0i[8];
        const float yr = bl ? g1r[9] : g0r[9], yi = bl ? g1i[9] : g0i[9];
        tlr[a2] = xr * yr - xi * yi; tli[a2] = xr * yi + xi * yr;
      }
    }
#pragma unroll
    for (int i = 0; i < 16; ++i) {
      const float pr = thr[i >> 2] * tlr[i & 3] - thi[i >> 2] * tli[i & 3];
      const float pi = thr[i >> 2] * tli[i & 3] + thi[i >> 2] * tlr[i & 3];
      ar[i] = Fr * pr - Fi * pi;
      ai[i] = Fr * pi + Fi * pr;
    }
  }

  // ---- 50 Rot gates -------------------------------------------------------
  {
    const float4 uA0 = *(const float4*)(g_rots + NQ * 8);
    const float4 uB0 = *(const float4*)(g_rots + NQ * 8 + 4);
    run_gates<0>(uA0, uB0, ar, ai, lane);
  }

  // ---- Z expectations via 4-bit Walsh-Hadamard transform ------------------
  float pb[16];
#pragma unroll
  for (int i = 0; i < 16; ++i) pb[i] = ar[i] * ar[i] + ai[i] * ai[i];
#pragma unroll
  for (int lev = 1; lev < 16; lev <<= 1) {
#pragma unroll
    for (int i = 0; i < 16; ++i) {
      if (!(i & lev)) {
        const float A = pb[i], Bv = pb[i | lev];
        pb[i] = A + Bv;
        pb[i | lev] = A - Bv;
      }
    }
  }
#pragma unroll
  for (int q = 0; q < NQ; ++q) {
    const int R = (int)SCH.Rfin[9 - q];
    const int Rl = R & 15, Rh = R >> 4;
    float t = pb[Rl];
    if (Rh != 0) {
      const bool ph = (__popc(lane & Rh) & 1) != 0;
      t = ph ? -t : t;
    }
    t = red64_l63(t);
    if (lane == 63) out[s * NQ + q] = t;
  }
}

extern "C" void kernel_launch(void* const* d_in, const int* in_sizes, int n_in,
                              void* d_out, int out_size, void* d_ws, size_t ws_size,
                              hipStream_t stream) {
  const float* x   = (const float*)d_in[0];
  const float* W   = (const float*)d_in[1];
  const float* b   = (const float*)d_in[2];
  const float* wts = (const float*)d_in[3];
  float* out = (float*)d_out;
  const int B = in_sizes[0] / 64;

  setup_rots_kernel<<<1, 64, 0, stream>>>(wts);
  qlayer_kernel<<<B / 4, 256, 0, stream>>>(x, W, b, out);
}

// Round 9
// 252.505 us; speedup vs baseline: 1.1714x; 1.1714x over previous
//
#include <hip/hip_runtime.h>

// ---------------------------------------------------------------------------
// QuantumLayer: B=16384 states of 10 qubits (DIM=1024 complex amps).
// One wave (64 lanes) per state; each lane holds 16 complex amps in VGPRs.
// Amp index k (10 bits): lane = k>>4 (storage bits 9..4), reg = k&15 (bits 3..0).
// CNOTs are compile-time GF(2) index relabeling (matrix S); each Rot gate acts
// along direction v = S e_b with side bit parity(R & k), R = row of S^{-1}.
// Cross-lane transport: ds_swizzle (xor<32) / ds_bpermute (xor>=32) -- R8
// proved VALU-routed transport (DPP/permlane) regresses; R4 structure is the
// proven-fast baseline (211 us).
// R9 vs R4: (1) setup kernel folded into qlayer -- first 60 threads per block
// compute the 60 Rot matrices into LDS (broadcast reads, 1.9 KB), killing the
// separate dispatch (~40 us of bench time) and moving coefficient loads from
// L2 to LDS; (2) gate math as explicit fmaf chains with inline negs
// (guaranteed 1 mul + 3 fma per component, negs fold into VOP3 modifiers).
// ---------------------------------------------------------------------------

namespace {

constexpr int NQ = 10;
constexpr int NGATES = 50;   // Rot gates of layers 1..5 (layer 0 fused into init)

struct Sched {
  unsigned v[NGATES];
  unsigned R[NGATES];
  unsigned Rfin[NQ];
  bool ok;
};

constexpr int par(unsigned x) { int p = 0; while (x) { p ^= 1; x &= x - 1; } return p; }

constexpr Sched make_sched() {
  Sched s{};
  unsigned cols[NQ] = {};
  unsigned rows[NQ] = {};
  for (int b = 0; b < NQ; ++b) { cols[b] = 1u << b; rows[b] = 1u << b; }
  int g = 0;
  for (int l = 0; l < 6; ++l) {
    if (l > 0) {
      for (int w = 0; w < NQ; ++w) {
        int b = 9 - w;
        s.v[g] = cols[b];
        s.R[g] = rows[b];
        ++g;
      }
    }
    int r = l % 9 + 1;
    for (int w = 0; w < NQ; ++w) {
      int c = w, t = (w + r) % NQ;
      int cb = 9 - c, tb = 9 - t;
      cols[cb] ^= cols[tb];
      rows[tb] ^= rows[cb];
    }
  }
  for (int b = 0; b < NQ; ++b) s.Rfin[b] = rows[b];
  bool ok = true;
  for (int a = 0; a < NQ; ++a)
    for (int b = 0; b < NQ; ++b)
      if (par(rows[a] & cols[b]) != (a == b ? 1 : 0)) ok = false;
  s.ok = ok;
  return s;
}

constexpr Sched SCH = make_sched();
static_assert(SCH.ok, "GF(2) schedule inconsistent");

} // namespace

// ---- cross-lane primitives (zero per-value VALU overhead) ------------------
__device__ __forceinline__ float bperm1(int baddr, float v) {
  return __int_as_float(__builtin_amdgcn_ds_bpermute(baddr, __float_as_int(v)));
}

template<int M>
__device__ __forceinline__ float swz1(float v) {
  // BitMode xor swizzle within 32-lane groups: offset = (xor<<10) | and_mask 0x1F
  return __int_as_float(__builtin_amdgcn_ds_swizzle(__float_as_int(v), (M << 10) | 0x1F));
}

typedef unsigned uint2v __attribute__((ext_vector_type(2)));

// full-wave add-reduction: 5 swizzle-xor levels + permlane32_swap half merge
// (orientation-independent: {r.x,r.y} = {lo-total, hi-total} as a set)
__device__ __forceinline__ float red64(float t) {
  t += swz1<1>(t);  t += swz1<2>(t);  t += swz1<4>(t);
  t += swz1<8>(t);  t += swz1<16>(t);
  uint2v r = __builtin_amdgcn_permlane32_swap(__float_as_uint(t), __float_as_uint(t),
                                              false, false);
  return __uint_as_float(r.x) + __uint_as_float(r.y);
}

// ---- one Rot gate along compile-time direction v, side-row R ---------------
template<int G>
__device__ __forceinline__ void apply_gate(const float4 uA, const float4 uB,
                                           float (&ar)[16], float (&ai)[16],
                                           const int lane) {
  constexpr int v  = (int)SCH.v[G];
  constexpr int R  = (int)SCH.R[G];
  constexpr int vl = v & 15, vh = v >> 4;
  constexpr int Rl = R & 15, Rh = R >> 4;

  bool ph = false;
  if constexpr (Rh != 0) ph = (__popc(lane & Rh) & 1) != 0;
  // class A: parity(i&Rl)==0 -> side==ph ; class B: side==!ph
  const float dAr = ph ? uB.z : uA.x, dAi = ph ? uB.w : uA.y;
  const float oAr = ph ? uB.x : uA.z, oAi = ph ? uB.y : uA.w;
  const float dBr = ph ? uA.x : uB.z, dBi = ph ? uA.y : uB.w;
  const float oBr = ph ? uA.z : uB.x, oBi = ph ? uA.w : uB.y;

  if constexpr (vh == 0) {
    // in-register pairs (i, i^vl)
#pragma unroll
    for (int i = 0; i < 16; ++i) {
      const int j = i ^ vl;
      if (j > i) {
        const bool ci = (__popc(i & Rl) & 1) != 0;   // compile-time after unroll
        const bool cj = (__popc(j & Rl) & 1) != 0;
        const float d0r = ci ? dBr : dAr, d0i = ci ? dBi : dAi;
        const float o0r = ci ? oBr : oAr, o0i = ci ? oBi : oAi;
        const float d1r = cj ? dBr : dAr, d1i = cj ? dBi : dAi;
        const float o1r = cj ? oBr : oAr, o1i = cj ? oBi : oAi;
        const float xr = ar[i], xi = ai[i], yr = ar[j], yi = ai[j];
        ar[i] = fmaf(-o0i, yi, fmaf(o0r, yr, fmaf(-d0i, xi, d0r * xr)));
        ai[i] = fmaf( o0i, yr, fmaf(o0r, yi, fmaf( d0i, xr, d0r * xi)));
        ar[j] = fmaf(-o1i, xi, fmaf(o1r, xr, fmaf(-d1i, yi, d1r * yr)));
        ai[j] = fmaf( o1i, xr, fmaf(o1r, xi, fmaf( d1i, yr, d1r * yi)));
      }
    }
  } else {
    int baddr = 0;
    if constexpr (vh >= 32) baddr = (lane ^ vh) << 2;  // hoisted: 2 VALU per gate
    auto fetch = [&](float x) -> float {
      if constexpr (vh < 32) return swz1<vh>(x);
      else                   return bperm1(baddr, x);
    };

    if constexpr (vl == 0) {
      // pure cross-lane: partner (lane^vh, i)
#pragma unroll
      for (int i = 0; i < 16; ++i) {
        const float pr = fetch(ar[i]);
        const float pi = fetch(ai[i]);
        const bool ci = (__popc(i & Rl) & 1) != 0;
        const float ddr = ci ? dBr : dAr, ddi = ci ? dBi : dAi;
        const float oor = ci ? oBr : oAr, ooi = ci ? oBi : oAi;
        const float xr = ar[i], xi = ai[i];
        ar[i] = fmaf(-ooi, pi, fmaf(oor, pr, fmaf(-ddi, xi, ddr * xr)));
        ai[i] = fmaf( ooi, pr, fmaf(oor, pi, fmaf( ddi, xr, ddr * xi)));
      }
    } else {
      // mixed: (lane,i) pairs with (lane^vh, i^vl); fetch before write per pair
#pragma unroll
      for (int i = 0; i < 16; ++i) {
        const int j = i ^ vl;
        if (j > i) {
          const float qjr = fetch(ar[j]);
          const float qji = fetch(ai[j]);
          const float qir = fetch(ar[i]);
          const float qii = fetch(ai[i]);
          const bool ci = (__popc(i & Rl) & 1) != 0;
          const bool cj = (__popc(j & Rl) & 1) != 0;
          const float d0r = ci ? dBr : dAr, d0i = ci ? dBi : dAi;
          const float o0r = ci ? oBr : oAr, o0i = ci ? oBi : oAi;
          const float d1r = cj ? dBr : dAr, d1i = cj ? dBi : dAi;
          const float o1r = cj ? oBr : oAr, o1i = cj ? oBi : oAi;
          const float xr = ar[i], xi = ai[i], yr = ar[j], yi = ai[j];
          ar[i] = fmaf(-o0i, qji, fmaf(o0r, qjr, fmaf(-d0i, xi, d0r * xr)));
          ai[i] = fmaf( o0i, qjr, fmaf(o0r, qji, fmaf( d0i, xr, d0r * xi)));
          ar[j] = fmaf(-o1i, qii, fmaf(o1r, qir, fmaf(-d1i, yi, d1r * yr)));
          ai[j] = fmaf( o1i, qir, fmaf(o1r, qii, fmaf( d1i, yr, d1r * yi)));
        }
      }
    }
  }
}

// Distance-1 pipeline: gate G+1's coefficient LDS reads issue BEFORE gate G's
// FMA block (hides lgkm latency under compute).
template<int G>
__device__ __forceinline__ void run_gates(const float4 uA, const float4 uB,
                                          const float* rots_s,
                                          float (&ar)[16], float (&ai)[16],
                                          const int lane) {
  float4 nA, nB;
  if constexpr (G + 1 < NGATES) {
    nA = *(const float4*)(rots_s + (NQ + G + 1) * 8);
    nB = *(const float4*)(rots_s + (NQ + G + 1) * 8 + 4);
  }
  apply_gate<G>(uA, uB, ar, ai, lane);
  if constexpr (G + 1 < NGATES) run_gates<G + 1>(nA, nB, rots_s, ar, ai, lane);
}

__launch_bounds__(256)
__global__ void qlayer_kernel(const float* __restrict__ x,
                              const float* __restrict__ W,
                              const float* __restrict__ bias,
                              const float* __restrict__ wts,
                              float* __restrict__ out) {
  __shared__ float rots_s[60 * 8];   // 1.92 KB: all 60 Rot matrices

  const int tid  = threadIdx.x;
  const int lane = tid & 63;
  const int s = blockIdx.x * 4 + (tid >> 6);

  // ---- in-block setup: thread t (<60) computes Rot matrix t ---------------
  if (tid < 60) {
    const float phi = wts[tid * 3 + 0], th = wts[tid * 3 + 1], om = wts[tid * 3 + 2];
    float c, sn;
    sincosf(0.5f * th, &sn, &c);
    float ca, sa, cb, sb;
    sincosf(0.5f * (phi + om), &sa, &ca);
    sincosf(0.5f * (phi - om), &sb, &cb);
    float* o = rots_s + tid * 8;
    o[0] =  ca * c;   o[1] = -sa * c;    // u00 = e^{-i(phi+om)/2} cos(th/2)
    o[2] = -cb * sn;  o[3] = -sb * sn;   // u01 = -e^{+i(phi-om)/2} sin(th/2)
    o[4] =  cb * sn;  o[5] = -sb * sn;   // u10 = e^{-i(phi-om)/2} sin(th/2)
    o[6] =  ca * c;   o[7] =  sa * c;    // u11 = e^{+i(phi+om)/2} cos(th/2)
  }

  // ---- angles = x @ W^T + b ; RX cos/sin (overlaps with setup) ------------
  const float xl = x[s * 64 + lane];
  float wl[NQ];
#pragma unroll
  for (int w = 0; w < NQ; ++w) wl[w] = W[w * 64 + lane];

  float cw[NQ], sw[NQ];
#pragma unroll
  for (int w = 0; w < NQ; ++w) {
    const float p = red64(xl * wl[w]);
    const float half = 0.5f * (p + bias[w]);
    float ss, cc;
    __sincosf(half, &ss, &cc);
    sw[w] = ss; cw[w] = cc;
  }

  __syncthreads();   // rots_s ready

  // ---- fused per-qubit vector g_w = Rot0_w * RX_w * |0> -------------------
  float g0r[NQ], g0i[NQ], g1r[NQ], g1i[NQ];
#pragma unroll
  for (int w = 0; w < NQ; ++w) {
    const float4 uA = *(const float4*)(rots_s + w * 8);
    const float4 uB = *(const float4*)(rots_s + w * 8 + 4);
    const float c = cw[w], sn = sw[w];
    g0r[w] = fmaf(uA.w, sn, uA.x * c);
    g0i[w] = fmaf(-uA.z, sn, uA.y * c);
    g1r[w] = fmaf(uB.w, sn, uB.x * c);
    g1i[w] = fmaf(-uB.z, sn, uB.y * c);
  }

  // ---- product state ------------------------------------------------------
  float Fr, Fi;
  {
    const int b0 = (lane >> 5) & 1;
    Fr = b0 ? g1r[0] : g0r[0];
    Fi = b0 ? g1i[0] : g0i[0];
#pragma unroll
    for (int w = 1; w < 6; ++w) {
      const int bt = (lane >> (5 - w)) & 1;
      const float gr = bt ? g1r[w] : g0r[w];
      const float gi = bt ? g1i[w] : g0i[w];
      const float nr = fmaf(-Fi, gi, Fr * gr);
      const float ni = fmaf( Fi, gr, Fr * gi);
      Fr = nr; Fi = ni;
    }
  }

  float ar[16], ai[16];
  {
    float thr[4], thi[4], tlr[4], tli[4];
#pragma unroll
    for (int a2 = 0; a2 < 4; ++a2) {
      const int bh = (a2 >> 1) & 1, bl = a2 & 1;
      {
        const float xr = bh ? g1r[6] : g0r[6], xi = bh ? g1i[6] : g0i[6];
        const float yr = bl ? g1r[7] : g0r[7], yi = bl ? g1i[7] : g0i[7];
        thr[a2] = fmaf(-xi, yi, xr * yr); thi[a2] = fmaf(xi, yr, xr * yi);
      }
      {
        const float xr = bh ? g1r[8] : g0r[8], xi = bh ? g1i[8] : g0i[8];
        const float yr = bl ? g1r[9] : g0r[9], yi = bl ? g1i[9] : g0i[9];
        tlr[a2] = fmaf(-xi, yi, xr * yr); tli[a2] = fmaf(xi, yr, xr * yi);
      }
    }
#pragma unroll
    for (int i = 0; i < 16; ++i) {
      const float pr = fmaf(-thi[i >> 2], tli[i & 3], thr[i >> 2] * tlr[i & 3]);
      const float pi = fmaf( thi[i >> 2], tlr[i & 3], thr[i >> 2] * tli[i & 3]);
      ar[i] = fmaf(-Fi, pi, Fr * pr);
      ai[i] = fmaf( Fi, pr, Fr * pi);
    }
  }

  // ---- 50 Rot gates (coefficients from LDS, distance-1 prefetch) ----------
  {
    const float4 uA0 = *(const float4*)(rots_s + NQ * 8);
    const float4 uB0 = *(const float4*)(rots_s + NQ * 8 + 4);
    run_gates<0>(uA0, uB0, rots_s, ar, ai, lane);
  }

  // ---- Z expectations via 4-bit Walsh-Hadamard transform ------------------
  float pb[16];
#pragma unroll
  for (int i = 0; i < 16; ++i) pb[i] = fmaf(ai[i], ai[i], ar[i] * ar[i]);
#pragma unroll
  for (int lev = 1; lev < 16; lev <<= 1) {
#pragma unroll
    for (int i = 0; i < 16; ++i) {
      if (!(i & lev)) {
        const float A = pb[i], Bv = pb[i | lev];
        pb[i] = A + Bv;
        pb[i | lev] = A - Bv;
      }
    }
  }
#pragma unroll
  for (int q = 0; q < NQ; ++q) {
    const int R = (int)SCH.Rfin[9 - q];
    const int Rl = R & 15, Rh = R >> 4;
    float t = pb[Rl];
    if (Rh != 0) {
      const bool ph = (__popc(lane & Rh) & 1) != 0;
      t = ph ? -t : t;
    }
    t = red64(t);
    if (lane == 0) out[s * NQ + q] = t;
  }
}

extern "C" void kernel_launch(void* const* d_in, const int* in_sizes, int n_in,
                              void* d_out, int out_size, void* d_ws, size_t ws_size,
                              hipStream_t stream) {
  const float* x   = (const float*)d_in[0];
  const float* W   = (const float*)d_in[1];
  const float* b   = (const float*)d_in[2];
  const float* wts = (const float*)d_in[3];
  float* out = (float*)d_out;
  const int B = in_sizes[0] / 64;

  qlayer_kernel<<<B / 4, 256, 0, stream>>>(x, W, b, wts, out);
}